// Round 2
// baseline (753.885 us; speedup 1.0000x reference)
//
#include <hip/hip_runtime.h>

typedef short bf16x8 __attribute__((ext_vector_type(8)));
typedef float f32x4 __attribute__((ext_vector_type(4)));

#define INV_SQRT_2F  0.70710678118654752440f
#define INV_SQRT_NBF 0.35355339059327376220f

static const int E_CNT = 200000;

// ws layout (ushort units), total 38,531,072 ushorts = 77.06 MB
//   WT   [0          .. 131,072)    weights (77,824 used)
//   A    [131,072    .. 25,731,072) q (E*64, dead after K2) then u_ts (E*128)
//   B    [25,731,072 .. 38,531,072) x (E*64)
#define WS_OFF_Q    131072
#define WS_OFF_UTS  131072
#define WS_OFF_X    25731072

// Wt offsets (ushort units), layout [n][Kp] (transposed, K zero-padded to Kp)
#define WT_MRBF 0       // [128][128]
#define WT_RBF  16384   // [128][32]  (K=16 padded)
#define WT_MCBF 20480   // [64][128]
#define WT_CBF  28672   // [64][32]   (K=16 padded)
#define WT_MSBF 30720   // [64][64]
#define WT_SBF  34816   // [64][32]
#define WT_DIR  36864   // [128][64]
#define WT_ST   45056   // [128][128]
#define WT_TS   61440   // [128][128]

// ---------------- helpers ----------------
__device__ __forceinline__ unsigned short f2bf(float f) {
  union { float f; unsigned u; } x; x.f = f;
  unsigned u = x.u;
  u += 0x7fffu + ((u >> 16) & 1u);   // RNE
  return (unsigned short)(u >> 16);
}
__device__ __forceinline__ float bflo(unsigned u) {
  union { unsigned u; float f; } x; x.u = u << 16; return x.f;
}
__device__ __forceinline__ float bfhi(unsigned u) {
  union { unsigned u; float f; } x; x.u = u & 0xffff0000u; return x.f;
}
__device__ __forceinline__ unsigned pk2(float a, float b) {
  return (unsigned)f2bf(a) | ((unsigned)f2bf(b) << 16);
}
__device__ __forceinline__ float silu(float v) { return v / (1.0f + __expf(-v)); }
__device__ __forceinline__ f32x4 mfma16(bf16x8 a, bf16x8 b, f32x4 c) {
  return __builtin_amdgcn_mfma_f32_16x16x32_bf16(a, b, c, 0, 0, 0);
}
__device__ __forceinline__ bf16x8 zfrag() {
  bf16x8 z;
#pragma unroll
  for (int i = 0; i < 8; ++i) z[i] = (short)0;
  return z;
}
__device__ __forceinline__ bf16x8 pack8(const float* v) {
  union { bf16x8 f; unsigned u[4]; } x;
#pragma unroll
  for (int i = 0; i < 4; ++i) x.u[i] = pk2(v[2*i], v[2*i+1]);
  return x.f;
}
__device__ __forceinline__ bf16x8 ldg_frag(const unsigned short* p) {
  return *reinterpret_cast<const bf16x8*>(p);
}

// ---------------- prep: f32 W[K][N] -> bf16 Wt[n][Kp] (zero-padded K) ----------------
__global__ __launch_bounds__(256) void k_prep(
    const float* __restrict__ w0, const float* __restrict__ w1, const float* __restrict__ w2,
    const float* __restrict__ w3, const float* __restrict__ w4, const float* __restrict__ w5,
    const float* __restrict__ w6, const float* __restrict__ w7, const float* __restrict__ w8,
    unsigned short* __restrict__ WT)
{
  int i = blockIdx.x * 256 + threadIdx.x;   // grid covers exactly 77824
  const float* w; int off, K, N, lgKp;
  if      (i < 16384) { w = w0; off = 0;     K = 128; N = 128; lgKp = 7; }
  else if (i < 20480) { w = w1; off = 16384; K = 16;  N = 128; lgKp = 5; }
  else if (i < 28672) { w = w2; off = 20480; K = 128; N = 64;  lgKp = 7; }
  else if (i < 30720) { w = w3; off = 28672; K = 16;  N = 64;  lgKp = 5; }
  else if (i < 34816) { w = w4; off = 30720; K = 64;  N = 64;  lgKp = 6; }
  else if (i < 36864) { w = w5; off = 34816; K = 32;  N = 64;  lgKp = 5; }
  else if (i < 45056) { w = w6; off = 36864; K = 64;  N = 128; lgKp = 6; }
  else if (i < 61440) { w = w7; off = 45056; K = 128; N = 128; lgKp = 7; }
  else                { w = w8; off = 61440; K = 128; N = 128; lgKp = 7; }
  int local = i - off;
  int n = local >> lgKp;
  int k = local & ((1 << lgKp) - 1);
  float v = (k < K) ? w[k * N + n] : 0.0f;
  WT[i] = f2bf(v);
}

// ---------------- K1: m_st,rbf -> q (E,64) bf16 ----------------
// transposed MFMA: lane holds features {16ft+4g+i} of data-row m = lane&15
__global__ __launch_bounds__(256) void k_edge1(
    const float* __restrict__ m_st, const float* __restrict__ rbf,
    const unsigned short* __restrict__ WT, const float* __restrict__ scp,
    unsigned short* __restrict__ q_out)
{
  __shared__ __align__(16) unsigned short h_lds[4][2][2176];  // [wave][ct][16*136]
  const int tid = threadIdx.x;
  const int wv = tid >> 6, ln = tid & 63;
  const int m = ln & 15, g = ln >> 4;
  const float sc = scp[0];
  const unsigned short* WmrbfT = WT + WT_MRBF;
  const unsigned short* WrbfT  = WT + WT_RBF;
  const unsigned short* WmcbfT = WT + WT_MCBF;

  int r[2]; bool ok[2];
  r[0] = blockIdx.x * 128 + wv * 32 + m;
  r[1] = r[0] + 16;
  ok[0] = r[0] < E_CNT; ok[1] = r[1] < E_CNT;

  bf16x8 bA[2][4], bR[2];
#pragma unroll
  for (int ct = 0; ct < 2; ++ct) {
#pragma unroll
    for (int s = 0; s < 4; ++s) {
      float v[8];
      if (ok[ct]) {
        *(float4*)&v[0] = *(const float4*)(m_st + (size_t)r[ct]*128 + 32*s + 8*g);
        *(float4*)&v[4] = *(const float4*)(m_st + (size_t)r[ct]*128 + 32*s + 8*g + 4);
      } else {
#pragma unroll
        for (int i = 0; i < 8; ++i) v[i] = 0.0f;
      }
      bA[ct][s] = pack8(v);
    }
    if (ok[ct] && g < 2) {
      float v[8];
      *(float4*)&v[0] = *(const float4*)(rbf + (size_t)r[ct]*16 + 8*g);
      *(float4*)&v[4] = *(const float4*)(rbf + (size_t)r[ct]*16 + 8*g + 4);
      bR[ct] = pack8(v);
    } else bR[ct] = zfrag();
  }

  // h = silu(m_st@W_m_rbf) * (rbf@W_rbf) * scale_rbf   -> LDS (bf16)
#pragma unroll
  for (int ft = 0; ft < 8; ++ft) {
    f32x4 c1[2] = {{0,0,0,0},{0,0,0,0}};
#pragma unroll
    for (int s = 0; s < 4; ++s) {
      bf16x8 a = ldg_frag(WmrbfT + ((ft*16 + m)*128 + 32*s + 8*g));
      c1[0] = mfma16(a, bA[0][s], c1[0]);
      c1[1] = mfma16(a, bA[1][s], c1[1]);
    }
    bf16x8 a2 = ldg_frag(WrbfT + ((ft*16 + m)*32 + 8*g));
#pragma unroll
    for (int ct = 0; ct < 2; ++ct) {
      f32x4 c2 = {0,0,0,0};
      c2 = mfma16(a2, bR[ct], c2);
      unsigned p0 = pk2(silu(c1[ct][0])*c2[0]*sc, silu(c1[ct][1])*c2[1]*sc);
      unsigned p1 = pk2(silu(c1[ct][2])*c2[2]*sc, silu(c1[ct][3])*c2[3]*sc);
      *(uint2*)&h_lds[wv][ct][m*136 + ft*16 + 4*g] = make_uint2(p0, p1);
    }
  }
  asm volatile("s_waitcnt lgkmcnt(0)" ::: "memory");

  bf16x8 bH[2][4];
#pragma unroll
  for (int ct = 0; ct < 2; ++ct)
#pragma unroll
    for (int s = 0; s < 4; ++s)
      bH[ct][s] = *(const bf16x8*)&h_lds[wv][ct][m*136 + 32*s + 8*g];

  // q = silu(h @ W_m_cbf)
#pragma unroll
  for (int ft = 0; ft < 4; ++ft) {
    f32x4 c[2] = {{0,0,0,0},{0,0,0,0}};
#pragma unroll
    for (int s = 0; s < 4; ++s) {
      bf16x8 a = ldg_frag(WmcbfT + ((ft*16 + m)*128 + 32*s + 8*g));
      c[0] = mfma16(a, bH[0][s], c[0]);
      c[1] = mfma16(a, bH[1][s], c[1]);
    }
#pragma unroll
    for (int ct = 0; ct < 2; ++ct) {
      if (ok[ct]) {
        unsigned p0 = pk2(silu(c[ct][0]), silu(c[ct][1]));
        unsigned p1 = pk2(silu(c[ct][2]), silu(c[ct][3]));
        *(uint2*)(q_out + (size_t)r[ct]*64 + ft*16 + 4*g) = make_uint2(p0, p1);
      }
    }
  }
}

// ---------------- K2: per (e,nb) row -> x (E,64) bf16 ----------------
__global__ __launch_bounds__(256) void k_quad(
    const float* __restrict__ cbf, const float* __restrict__ sbf,
    const int* __restrict__ idx_s, const int* __restrict__ bidx1, const int* __restrict__ bidx2,
    const unsigned short* __restrict__ WT,
    const float* __restrict__ sccp, const float* __restrict__ scsp,
    const unsigned short* __restrict__ q_in, unsigned short* __restrict__ x_out)
{
  __shared__ __align__(16) unsigned short qn_lds[4][1152];   // [wave][16*72]
  const int tid = threadIdx.x;
  const int wv = tid >> 6, ln = tid & 63;
  const int m = ln & 15, g = ln >> 4;
  const float sc_c = sccp[0], sc_s = scsp[0];
  const unsigned short* WcbfT  = WT + WT_CBF;
  const unsigned short* WmsbfT = WT + WT_MSBF;
  const unsigned short* WsbfT  = WT + WT_SBF;

  // hoist all weight fragments into registers (reused across 8 row-tiles)
  bf16x8 aC[4], aT[4][2], aS[4];
#pragma unroll
  for (int ft = 0; ft < 4; ++ft) {
    aC[ft]    = ldg_frag(WcbfT  + ((ft*16 + m)*32 + 8*g));
    aT[ft][0] = ldg_frag(WmsbfT + ((ft*16 + m)*64 + 8*g));
    aT[ft][1] = ldg_frag(WmsbfT + ((ft*16 + m)*64 + 32 + 8*g));
    aS[ft]    = ldg_frag(WsbfT  + ((ft*16 + m)*32 + 8*g));
  }

  const int base = blockIdx.x * 512 + wv * 128;   // 1.6M rows, exact cover

  // prefetch all index chains (8 independent chains overlap their latency)
  int b1a[8], b2a[8];
#pragma unroll
  for (int it = 0; it < 8; ++it) {
    int rr = base + it*16 + m;
    int e  = rr >> 3;
    int s1 = idx_s[e];
    int bb = s1 * 8 + (rr & 7);
    b1a[it] = bidx1[bb];
    b2a[it] = bidx2[bb];
  }

  for (int it = 0; it < 8; ++it) {
    const int r = base + it*16 + m;
    const int e = r >> 3;
    const int b1 = b1a[it], b2 = b2a[it];

    bf16x8 bC;
    if (g < 2) {
      float v[8];
      *(float4*)&v[0] = *(const float4*)(cbf + (size_t)r*16 + 8*g);
      *(float4*)&v[4] = *(const float4*)(cbf + (size_t)r*16 + 8*g + 4);
      bC = pack8(v);
    } else bC = zfrag();
    bf16x8 bS;
    {
      float v[8];
      *(float4*)&v[0] = *(const float4*)(sbf + (size_t)r*32 + 8*g);
      *(float4*)&v[4] = *(const float4*)(sbf + (size_t)r*32 + 8*g + 4);
      bS = pack8(v);
    }

    // qn = (q[b1]+q[b2])/sqrt2 * (cbf@W_cbf) * scale_cbf  -> LDS (bf16)
#pragma unroll
    for (int ft = 0; ft < 4; ++ft) {
      uint2 u1 = *(const uint2*)(q_in + (size_t)b1*64 + ft*16 + 4*g);
      uint2 u2 = *(const uint2*)(q_in + (size_t)b2*64 + ft*16 + 4*g);
      f32x4 cp = {0,0,0,0};
      cp = mfma16(aC[ft], bC, cp);
      float n0 = (bflo(u1.x) + bflo(u2.x)) * INV_SQRT_2F * cp[0] * sc_c;
      float n1 = (bfhi(u1.x) + bfhi(u2.x)) * INV_SQRT_2F * cp[1] * sc_c;
      float n2 = (bflo(u1.y) + bflo(u2.y)) * INV_SQRT_2F * cp[2] * sc_c;
      float n3 = (bfhi(u1.y) + bfhi(u2.y)) * INV_SQRT_2F * cp[3] * sc_c;
      *(uint2*)&qn_lds[wv][m*72 + ft*16 + 4*g] = make_uint2(pk2(n0,n1), pk2(n2,n3));
    }
    asm volatile("s_waitcnt lgkmcnt(0)" ::: "memory");
    bf16x8 bQ0 = *(const bf16x8*)&qn_lds[wv][m*72 + 8*g];
    bf16x8 bQ1 = *(const bf16x8*)&qn_lds[wv][m*72 + 32 + 8*g];

    // qn2 = silu(qn@W_m_sbf) * (sbf@W_sbf) * scale_sbf ; x = sum over nb
#pragma unroll
    for (int ft = 0; ft < 4; ++ft) {
      f32x4 ctv = {0,0,0,0};
      ctv = mfma16(aT[ft][0], bQ0, ctv);
      ctv = mfma16(aT[ft][1], bQ1, ctv);
      f32x4 cs = {0,0,0,0};
      cs = mfma16(aS[ft], bS, cs);
      float o[4];
#pragma unroll
      for (int i = 0; i < 4; ++i) {
        float v = silu(ctv[i]) * cs[i] * sc_s;
        v += __shfl_xor(v, 1);
        v += __shfl_xor(v, 2);
        v += __shfl_xor(v, 4);
        o[i] = v * INV_SQRT_NBF;
      }
      if ((m & 7) == 0) {
        *(uint2*)(x_out + (size_t)e*64 + ft*16 + 4*g) = make_uint2(pk2(o[0],o[1]), pk2(o[2],o[3]));
      }
    }
    asm volatile("" ::: "memory");   // keep next iter's LDS writes below this iter's reads
  }
}

// ---------------- K3: x -> u_st (f32, direct to out) and u_ts (bf16 table) ----------------
__global__ __launch_bounds__(256) void k_edge2(
    const unsigned short* __restrict__ x_in, const unsigned short* __restrict__ WT,
    float* __restrict__ out_ust, unsigned short* __restrict__ uts)
{
  __shared__ __align__(16) unsigned short t_lds[4][2][2176];
  const int tid = threadIdx.x;
  const int wv = tid >> 6, ln = tid & 63;
  const int m = ln & 15, g = ln >> 4;
  const unsigned short* WdirT = WT + WT_DIR;
  const unsigned short* WstT  = WT + WT_ST;
  const unsigned short* WtsT  = WT + WT_TS;

  int r[2]; bool ok[2];
  r[0] = blockIdx.x * 128 + wv * 32 + m;
  r[1] = r[0] + 16;
  ok[0] = r[0] < E_CNT; ok[1] = r[1] < E_CNT;

  bf16x8 bx[2][2];
#pragma unroll
  for (int ct = 0; ct < 2; ++ct) {
    if (ok[ct]) {
      bx[ct][0] = *(const bf16x8*)(x_in + (size_t)r[ct]*64 + 8*g);
      bx[ct][1] = *(const bf16x8*)(x_in + (size_t)r[ct]*64 + 32 + 8*g);
    } else { bx[ct][0] = zfrag(); bx[ct][1] = zfrag(); }
  }

  // t = silu(x @ W_dir) -> LDS
#pragma unroll
  for (int ft = 0; ft < 8; ++ft) {
    f32x4 c[2] = {{0,0,0,0},{0,0,0,0}};
#pragma unroll
    for (int s = 0; s < 2; ++s) {
      bf16x8 a = ldg_frag(WdirT + ((ft*16 + m)*64 + 32*s + 8*g));
      c[0] = mfma16(a, bx[0][s], c[0]);
      c[1] = mfma16(a, bx[1][s], c[1]);
    }
#pragma unroll
    for (int ct = 0; ct < 2; ++ct) {
      unsigned p0 = pk2(silu(c[ct][0]), silu(c[ct][1]));
      unsigned p1 = pk2(silu(c[ct][2]), silu(c[ct][3]));
      *(uint2*)&t_lds[wv][ct][m*136 + ft*16 + 4*g] = make_uint2(p0, p1);
    }
  }
  asm volatile("s_waitcnt lgkmcnt(0)" ::: "memory");

  bf16x8 bt[2][4];
#pragma unroll
  for (int ct = 0; ct < 2; ++ct)
#pragma unroll
    for (int s = 0; s < 4; ++s)
      bt[ct][s] = *(const bf16x8*)&t_lds[wv][ct][m*136 + 32*s + 8*g];

  // u_st = silu(t @ W_st) -> f32 directly into out (K4 finishes the combine)
#pragma unroll
  for (int ft = 0; ft < 8; ++ft) {
    f32x4 c[2] = {{0,0,0,0},{0,0,0,0}};
#pragma unroll
    for (int s = 0; s < 4; ++s) {
      bf16x8 a = ldg_frag(WstT + ((ft*16 + m)*128 + 32*s + 8*g));
      c[0] = mfma16(a, bt[0][s], c[0]);
      c[1] = mfma16(a, bt[1][s], c[1]);
    }
#pragma unroll
    for (int ct = 0; ct < 2; ++ct) {
      if (ok[ct]) {
        float4 o;
        o.x = silu(c[ct][0]); o.y = silu(c[ct][1]);
        o.z = silu(c[ct][2]); o.w = silu(c[ct][3]);
        *(float4*)(out_ust + (size_t)r[ct]*128 + ft*16 + 4*g) = o;
      }
    }
  }
  // u_ts = silu(t @ W_ts) -> bf16 table (gathered by K4)
#pragma unroll
  for (int ft = 0; ft < 8; ++ft) {
    f32x4 c[2] = {{0,0,0,0},{0,0,0,0}};
#pragma unroll
    for (int s = 0; s < 4; ++s) {
      bf16x8 a = ldg_frag(WtsT + ((ft*16 + m)*128 + 32*s + 8*g));
      c[0] = mfma16(a, bt[0][s], c[0]);
      c[1] = mfma16(a, bt[1][s], c[1]);
    }
#pragma unroll
    for (int ct = 0; ct < 2; ++ct) {
      if (ok[ct]) {
        unsigned p0 = pk2(silu(c[ct][0]), silu(c[ct][1]));
        unsigned p1 = pk2(silu(c[ct][2]), silu(c[ct][3]));
        *(uint2*)(uts + (size_t)r[ct]*128 + ft*16 + 4*g) = make_uint2(p0, p1);
      }
    }
  }
}

// ---------------- K4: out = (out + u_ts[idx_swap]) / sqrt2  (f32 RMW) ----------------
__global__ __launch_bounds__(256) void k_comb(
    const int* __restrict__ idx_swap, const unsigned short* __restrict__ uts,
    float* __restrict__ out)
{
  int i = blockIdx.x * 256 + threadIdx.x;   // E*32 threads, 4 elems each
  int e = i >> 5, p = i & 31;
  int se = idx_swap[e];
  float4 ua = *(const float4*)(out + (size_t)e*128 + p*4);
  uint2  ub = *(const uint2*)(uts + (size_t)se*128 + p*4);
  float4 o;
  o.x = (ua.x + bflo(ub.x)) * INV_SQRT_2F;
  o.y = (ua.y + bfhi(ub.x)) * INV_SQRT_2F;
  o.z = (ua.z + bflo(ub.y)) * INV_SQRT_2F;
  o.w = (ua.w + bfhi(ub.y)) * INV_SQRT_2F;
  *(float4*)(out + (size_t)e*128 + p*4) = o;
}

// ---------------- launch ----------------
extern "C" void kernel_launch(void* const* d_in, const int* in_sizes, int n_in,
                              void* d_out, int out_size, void* d_ws, size_t ws_size,
                              hipStream_t stream) {
  const float* m_st     = (const float*)d_in[0];
  const float* rbf      = (const float*)d_in[1];
  const float* cbf      = (const float*)d_in[2];
  const float* sbf      = (const float*)d_in[3];
  const int*   idx_s    = (const int*)d_in[4];
  const int*   idx_swap = (const int*)d_in[5];
  const int*   bidx1    = (const int*)d_in[6];
  const int*   bidx2    = (const int*)d_in[7];
  const float* W_m_rbf  = (const float*)d_in[8];
  const float* W_rbf    = (const float*)d_in[9];
  const float* W_m_cbf  = (const float*)d_in[10];
  const float* W_cbf    = (const float*)d_in[11];
  const float* W_m_sbf  = (const float*)d_in[12];
  const float* W_sbf    = (const float*)d_in[13];
  const float* W_dir    = (const float*)d_in[14];
  const float* W_st     = (const float*)d_in[15];
  const float* W_ts     = (const float*)d_in[16];
  const float* sc_rbf   = (const float*)d_in[17];
  const float* sc_cbf   = (const float*)d_in[18];
  const float* sc_sbf   = (const float*)d_in[19];

  unsigned short* WTp    = (unsigned short*)d_ws;
  unsigned short* q_ws   = WTp + WS_OFF_Q;
  unsigned short* uts_ws = WTp + WS_OFF_UTS;   // overwrites q (dead after K2)
  unsigned short* x_ws   = WTp + WS_OFF_X;

  k_prep<<<dim3(304), dim3(256), 0, stream>>>(
      W_m_rbf, W_rbf, W_m_cbf, W_cbf, W_m_sbf, W_sbf, W_dir, W_st, W_ts, WTp);
  k_edge1<<<dim3(1563), dim3(256), 0, stream>>>(m_st, rbf, WTp, sc_rbf, q_ws);
  k_quad<<<dim3(3125), dim3(256), 0, stream>>>(
      cbf, sbf, idx_s, bidx1, bidx2, WTp, sc_cbf, sc_sbf, q_ws, x_ws);
  k_edge2<<<dim3(1563), dim3(256), 0, stream>>>(x_ws, WTp, (float*)d_out, uts_ws);
  k_comb<<<dim3(25000), dim3(256), 0, stream>>>(idx_swap, uts_ws, (float*)d_out);
}